// Round 8
// baseline (38.534 us; speedup 1.0000x reference)
//
#include <hip/hip_runtime.h>
#include <hip/hip_bf16.h>
#include <math.h>

typedef __attribute__((ext_vector_type(8))) short short8v;  // 8 bf16 in 4 VGPRs
typedef __attribute__((ext_vector_type(4))) float f32x4;

__device__ inline unsigned short f2bf(float f) {
  return __builtin_bit_cast(unsigned short, __float2bfloat16(f));
}

// ---------------------------------------------------------------------------
// fold_packed (unchanged from round 6/7): pre-packed bf16 weight fragments,
// one element per thread, 36 blocks x 256, no LDS/sync.
// Layout: wsbf[lane][frag 0..17][elem 0..7] bf16, lane = 16*c + r:
//   frags 0..5  : hAf[go][f] = hA[(16go+r)][32f + 8c + e]
//   frags 6..11 : gAf[go][f]   same from gA
//   frags 12..17: w2f[go][f]   delta-permuted W2 (+ b2 at f=1,e=4)
// ---------------------------------------------------------------------------
__global__ __launch_bounds__(256) void fold_packed(
    const float* __restrict__ Wiv, const float* __restrict__ biv,
    const float* __restrict__ Wtv, const float* __restrict__ btv,
    const float* __restrict__ Wisv, const float* __restrict__ bisv,
    const float* __restrict__ Wtsv, const float* __restrict__ btsv,
    const float* __restrict__ Wm1, const float* __restrict__ bm1,
    const float* __restrict__ Wm2, const float* __restrict__ bm2,
    const float* __restrict__ Wg, const float* __restrict__ bg,
    unsigned short* __restrict__ wsbf) {
  const int idx = blockIdx.x * 256 + threadIdx.x;
  if (idx >= 64 * 18 * 8) return;
  const int lane = idx / 144;
  const int f18 = (idx >> 3) % 18;
  const int e = idx & 7;
  const int r = lane & 15, c = lane >> 4;

  float v = 0.f;
  if (f18 < 12) {
    const bool isH = (f18 < 6);
    const int q = isH ? f18 : f18 - 6;
    const int go = q >> 1, f = q & 1;
    const int row = go * 16 + r;
    const int j = f * 32 + c * 8 + e;
    if (isH) {
      if (j < 40) {
        for (int k = 0; k < 48; ++k) v += Wm1[row * 144 + 48 + k] * Wtv[k * 40 + j];
        for (int k = 0; k < 24; ++k) v += Wm1[row * 144 + 96 + k] * Wisv[k * 40 + j];
      } else if (j < 60) {
        const int jj = j - 40;
        for (int k = 0; k < 48; ++k) v += Wm1[row * 144 + k] * Wiv[k * 20 + jj];
        for (int k = 0; k < 24; ++k) v += Wm1[row * 144 + 120 + k] * Wtsv[k * 20 + jj];
      } else if (j == 60) {
        v = bm1[row];
        for (int k = 0; k < 48; ++k) v += Wm1[row * 144 + k] * biv[k];
        for (int k = 0; k < 48; ++k) v += Wm1[row * 144 + 48 + k] * btv[k];
        for (int k = 0; k < 24; ++k) v += Wm1[row * 144 + 96 + k] * bisv[k];
        for (int k = 0; k < 24; ++k) v += Wm1[row * 144 + 120 + k] * btsv[k];
      }
    } else {
      if (j < 40) {
        for (int k = 0; k < 48; ++k) v += Wg[row * 96 + 48 + k] * Wtv[k * 40 + j];
      } else if (j < 60) {
        const int jj = j - 40;
        for (int k = 0; k < 48; ++k) v += Wg[row * 96 + k] * Wiv[k * 20 + jj];
      } else if (j == 60) {
        v = bg[row];
        for (int k = 0; k < 48; ++k) v += Wg[row * 96 + k] * biv[k];
        for (int k = 0; k < 48; ++k) v += Wg[row * 96 + 48 + k] * btv[k];
      }
    }
  } else {
    const int q = f18 - 12;
    const int f = q & 1;
    const int row = (q >> 1) * 16 + r;
    if (f == 0) {
      const int col = (e < 4) ? (4 * c + e) : (16 + 4 * c + (e - 4));
      v = Wm2[row * 48 + col];
    } else {
      if (e < 4) v = Wm2[row * 48 + 32 + 4 * c + e];
      else if (e == 4) v = bm2[row];
    }
  }
  wsbf[idx] = f2bf(v);
}

// ---------------------------------------------------------------------------
// mfma_main: 128 rows/block, 4 waves x 32 rows (2 tiles). X staged to LDS via
// global_load_lds (fire-and-forget DMA: 30 KB in flight per block regardless
// of VGPR budget — rounds 4/6/7 showed the allocator caps VGPR-held MLP at
// ~2 TB/s). One vmcnt(0)+barrier, then ds_read_b128 fragments.
// ---------------------------------------------------------------------------
__device__ __forceinline__ void gld_lds16(const float* gsrc, float* ldst) {
  __builtin_amdgcn_global_load_lds(
      (const __attribute__((address_space(1))) void*)gsrc,
      (__attribute__((address_space(3))) void*)ldst, 16, 0, 0);
}

__device__ __forceinline__ void compute_tile(
    size_t rowbase, int r, int c,
    float4 i0, float4 i1, float4 b0, float4 b1,
    const short8v (&hAf)[3][2], const short8v (&gAf)[3][2],
    const short8v (&w2f)[3][2], float* __restrict__ out) {
  const f32x4 z = {0.f, 0.f, 0.f, 0.f};
  short8v xa0, xa1;
  xa0[0] = (short)f2bf(i0.x); xa0[1] = (short)f2bf(i0.y);
  xa0[2] = (short)f2bf(i0.z); xa0[3] = (short)f2bf(i0.w);
  xa0[4] = (short)f2bf(i1.x); xa0[5] = (short)f2bf(i1.y);
  xa0[6] = (short)f2bf(i1.z); xa0[7] = (short)f2bf(i1.w);
  xa1[0] = (short)f2bf(b0.x); xa1[1] = (short)f2bf(b0.y);
  xa1[2] = (short)f2bf(b0.z); xa1[3] = (short)f2bf(b0.w);
  xa1[4] = (short)f2bf(b1.x); xa1[5] = (short)f2bf(b1.y);
  xa1[6] = (short)f2bf(b1.z); xa1[7] = (short)f2bf(b1.w);

  f32x4 hacc[3], gacc[3];
#pragma unroll
  for (int go = 0; go < 3; ++go)
    hacc[go] = __builtin_amdgcn_mfma_f32_16x16x32_bf16(
        hAf[go][1], xa1,
        __builtin_amdgcn_mfma_f32_16x16x32_bf16(hAf[go][0], xa0, z, 0, 0, 0),
        0, 0, 0);
#pragma unroll
  for (int go = 0; go < 3; ++go)
    gacc[go] = __builtin_amdgcn_mfma_f32_16x16x32_bf16(
        gAf[go][1], xa1,
        __builtin_amdgcn_mfma_f32_16x16x32_bf16(gAf[go][0], xa0, z, 0, 0, 0),
        0, 0, 0);

  short8v hb0, hb1;
#pragma unroll
  for (int j = 0; j < 4; ++j) {
    hb0[j]     = (short)f2bf(fmaxf(hacc[0][j], 0.f));
    hb0[j + 4] = (short)f2bf(fmaxf(hacc[1][j], 0.f));
    hb1[j]     = (short)f2bf(fmaxf(hacc[2][j], 0.f));
  }
  hb1[4] = (c == 3) ? (short)0x3F80 : (short)0;  // bias-1.0 in exactly one k-slot
  hb1[5] = 0; hb1[6] = 0; hb1[7] = 0;

  f32x4 oacc[3];
#pragma unroll
  for (int go = 0; go < 3; ++go)
    oacc[go] = __builtin_amdgcn_mfma_f32_16x16x32_bf16(
        w2f[go][1], hb1,
        __builtin_amdgcn_mfma_f32_16x16x32_bf16(w2f[go][0], hb0, z, 0, 0, 0),
        0, 0, 0);

  float* orow = out + (rowbase + r) * 48;
#pragma unroll
  for (int go = 0; go < 3; ++go) {
    float4 v;
    v.x = fmaxf(oacc[go][0], 0.f) * __builtin_amdgcn_rcpf(1.f + __expf(-gacc[go][0]));
    v.y = fmaxf(oacc[go][1], 0.f) * __builtin_amdgcn_rcpf(1.f + __expf(-gacc[go][1]));
    v.z = fmaxf(oacc[go][2], 0.f) * __builtin_amdgcn_rcpf(1.f + __expf(-gacc[go][2]));
    v.w = fmaxf(oacc[go][3], 0.f) * __builtin_amdgcn_rcpf(1.f + __expf(-gacc[go][3]));
    *reinterpret_cast<float4*>(orow + 16 * go + 4 * c) = v;
  }
}

__global__ __launch_bounds__(256) void mfma_main(
    const float* __restrict__ img, const float* __restrict__ txt,
    const unsigned short* __restrict__ wsbf, float* __restrict__ out) {
  __shared__ __align__(16) float simg[128 * 40];  // 20480 B
  __shared__ __align__(16) float stxt[128 * 20];  // 10240 B
  const int tid = threadIdx.x;
  const int wave = tid >> 6;
  const int lane = tid & 63;
  const int r = lane & 15;
  const int c = lane >> 4;
  const size_t row0 = (size_t)blockIdx.x * 128;

  // ---- stage X to LDS: 30 fire-and-forget 1024B chunks (dest wave-uniform,
  //      source per-lane). All issued before any wait: 30 KB in flight. ----
  {
    const float* gi = img + row0 * 40;
#pragma unroll
    for (int j = wave; j < 20; j += 4)
      gld_lds16(gi + j * 256 + lane * 4, &simg[j * 256]);
    const float* gt = txt + row0 * 20;
#pragma unroll
    for (int j = wave; j < 10; j += 4)
      gld_lds16(gt + j * 256 + lane * 4, &stxt[j * 256]);
  }

  // weight fragments (L2-resident; overlap with staging DMA)
  const short8v* wp = reinterpret_cast<const short8v*>(wsbf) + lane * 18;
  short8v hAf[3][2], gAf[3][2], w2f[3][2];
#pragma unroll
  for (int go = 0; go < 3; ++go) {
    hAf[go][0] = wp[go * 2 + 0];      hAf[go][1] = wp[go * 2 + 1];
    gAf[go][0] = wp[6 + go * 2 + 0];  gAf[go][1] = wp[6 + go * 2 + 1];
    w2f[go][0] = wp[12 + go * 2 + 0]; w2f[go][1] = wp[12 + go * 2 + 1];
  }

  asm volatile("s_waitcnt vmcnt(0)" ::: "memory");
  __syncthreads();

  // ---- 2 tiles of 16 rows per wave, X fragments via ds_read_b128 ----
#pragma unroll
  for (int t = 0; t < 2; ++t) {
    const int lrow = wave * 32 + t * 16 + r;  // block-local row
    float4 xi0 = *(const float4*)&simg[lrow * 40 + c * 8];
    float4 xi1 = *(const float4*)&simg[lrow * 40 + c * 8 + 4];
    float4 xb0, xb1;
    if (c == 0) {
      xb0 = *(const float4*)&simg[lrow * 40 + 32];
      xb1 = *(const float4*)&simg[lrow * 40 + 36];
    } else if (c == 3) {
      xb0 = *(const float4*)&stxt[lrow * 20 + 16];
      xb1 = make_float4(1.f, 0.f, 0.f, 0.f);
    } else {
      xb0 = *(const float4*)&stxt[lrow * 20 + (c - 1) * 8];
      xb1 = *(const float4*)&stxt[lrow * 20 + (c - 1) * 8 + 4];
    }
    compute_tile(row0 + wave * 32 + t * 16, r, c, xi0, xi1, xb0, xb1,
                 hAf, gAf, w2f, out);
  }
}

extern "C" void kernel_launch(void* const* d_in, const int* in_sizes, int n_in,
                              void* d_out, int out_size, void* d_ws, size_t ws_size,
                              hipStream_t stream) {
  const float* img  = (const float*)d_in[0];
  const float* txt  = (const float*)d_in[1];
  const float* Wiv  = (const float*)d_in[6];
  const float* biv  = (const float*)d_in[7];
  const float* Wtv  = (const float*)d_in[12];
  const float* btv  = (const float*)d_in[13];
  const float* Wisv = (const float*)d_in[18];
  const float* bisv = (const float*)d_in[19];
  const float* Wtsv = (const float*)d_in[24];
  const float* btsv = (const float*)d_in[25];
  const float* Wm1  = (const float*)d_in[26];
  const float* bm1  = (const float*)d_in[27];
  const float* Wm2  = (const float*)d_in[28];
  const float* bm2  = (const float*)d_in[29];
  const float* Wg   = (const float*)d_in[30];
  const float* bg   = (const float*)d_in[31];
  float* out = (float*)d_out;
  unsigned short* wsbf = (unsigned short*)d_ws;  // 64*18*8 bf16 = 18432 B

  const int nrows = in_sizes[0] / 40;  // 262144

  hipLaunchKernelGGL(fold_packed, dim3(36), dim3(256), 0, stream,
                     Wiv, biv, Wtv, btv, Wisv, bisv, Wtsv, btsv,
                     Wm1, bm1, Wm2, bm2, Wg, bg, wsbf);

  const int grid = nrows / 128;  // 2048 blocks x 4 waves x 32 rows
  hipLaunchKernelGGL(mfma_main, dim3(grid), dim3(256), 0, stream,
                     img, txt, wsbf, out);
}

// Round 9
// 32.253 us; speedup vs baseline: 1.1947x; 1.1947x over previous
//
#include <hip/hip_runtime.h>
#include <hip/hip_bf16.h>
#include <math.h>

typedef __attribute__((ext_vector_type(8))) short short8v;  // 8 bf16 in 4 VGPRs
typedef __attribute__((ext_vector_type(4))) float f32x4;

__device__ inline unsigned short f2bf(float f) {
  return __builtin_bit_cast(unsigned short, __float2bfloat16(f));
}

// ---------------------------------------------------------------------------
// fold_packed: pre-packed bf16 weight fragments, FRAG-MAJOR layout:
//   wsbf[f18][lane][elem] bf16  (f18=0..17, lane=0..63, elem=0..7)
// so chunk f18 (1024 B) = fragment f18 across all 64 lanes -> global_load_lds
// chunks are linear AND per-lane ds_read_b128 at f*1024 + lane*16 is the
// canonical conflict-free LDS pattern.
//   frags 0..5  : hAf[go][f] = hA[(16go+r)][32f + 8c + e]   (lane = 16c + r)
//   frags 6..11 : gAf[go][f]   same from gA
//   frags 12..17: w2f[go][f]   delta-permuted W2 (+ b2 at f=1,e=4)
// hA/gA col j: 0..39 img coeff, 40..59 txt coeff, 60 bias, 61..63 zero.
// ---------------------------------------------------------------------------
__global__ __launch_bounds__(256) void fold_packed(
    const float* __restrict__ Wiv, const float* __restrict__ biv,
    const float* __restrict__ Wtv, const float* __restrict__ btv,
    const float* __restrict__ Wisv, const float* __restrict__ bisv,
    const float* __restrict__ Wtsv, const float* __restrict__ btsv,
    const float* __restrict__ Wm1, const float* __restrict__ bm1,
    const float* __restrict__ Wm2, const float* __restrict__ bm2,
    const float* __restrict__ Wg, const float* __restrict__ bg,
    unsigned short* __restrict__ wsbf) {
  const int idx = blockIdx.x * 256 + threadIdx.x;  // position in NEW layout
  if (idx >= 18 * 64 * 8) return;
  const int f18 = idx >> 9;          // /512
  const int lane = (idx >> 3) & 63;
  const int e = idx & 7;
  const int r = lane & 15, c = lane >> 4;

  float v = 0.f;
  if (f18 < 12) {
    const bool isH = (f18 < 6);
    const int q = isH ? f18 : f18 - 6;
    const int go = q >> 1, f = q & 1;
    const int row = go * 16 + r;
    const int j = f * 32 + c * 8 + e;
    if (isH) {
      if (j < 40) {
        for (int k = 0; k < 48; ++k) v += Wm1[row * 144 + 48 + k] * Wtv[k * 40 + j];
        for (int k = 0; k < 24; ++k) v += Wm1[row * 144 + 96 + k] * Wisv[k * 40 + j];
      } else if (j < 60) {
        const int jj = j - 40;
        for (int k = 0; k < 48; ++k) v += Wm1[row * 144 + k] * Wiv[k * 20 + jj];
        for (int k = 0; k < 24; ++k) v += Wm1[row * 144 + 120 + k] * Wtsv[k * 20 + jj];
      } else if (j == 60) {
        v = bm1[row];
        for (int k = 0; k < 48; ++k) v += Wm1[row * 144 + k] * biv[k];
        for (int k = 0; k < 48; ++k) v += Wm1[row * 144 + 48 + k] * btv[k];
        for (int k = 0; k < 24; ++k) v += Wm1[row * 144 + 96 + k] * bisv[k];
        for (int k = 0; k < 24; ++k) v += Wm1[row * 144 + 120 + k] * btsv[k];
      }
    } else {
      if (j < 40) {
        for (int k = 0; k < 48; ++k) v += Wg[row * 96 + 48 + k] * Wtv[k * 40 + j];
      } else if (j < 60) {
        const int jj = j - 40;
        for (int k = 0; k < 48; ++k) v += Wg[row * 96 + k] * Wiv[k * 20 + jj];
      } else if (j == 60) {
        v = bg[row];
        for (int k = 0; k < 48; ++k) v += Wg[row * 96 + k] * biv[k];
        for (int k = 0; k < 48; ++k) v += Wg[row * 96 + 48 + k] * btv[k];
      }
    }
  } else {
    const int q = f18 - 12;
    const int f = q & 1;
    const int row = (q >> 1) * 16 + r;
    if (f == 0) {
      const int col = (e < 4) ? (4 * c + e) : (16 + 4 * c + (e - 4));
      v = Wm2[row * 48 + col];
    } else {
      if (e < 4) v = Wm2[row * 48 + 32 + 4 * c + e];
      else if (e == 4) v = bm2[row];
    }
  }
  wsbf[idx] = f2bf(v);
}

// ---------------------------------------------------------------------------
// mfma_main: round-7 structure (4 waves x 64 rows = 4 tiles, direct per-lane
// X float4 loads issued upfront) + ONE change: weights staged to LDS once per
// block via global_load_lds, then per-lane ds_read_b128 (conflict-free,
// frag-major). Kills the L2 hot-spot: rounds 2-8 re-read the same 18 KB
// global region once per WAVE (8192x) -> ~150 MB through ~144 cache lines ->
// L2 channel serialization ~ the invariant 40 us wall.
// ---------------------------------------------------------------------------
__device__ __forceinline__ void gld_lds16(const float* gsrc, float* ldst) {
  __builtin_amdgcn_global_load_lds(
      (const __attribute__((address_space(1))) void*)gsrc,
      (__attribute__((address_space(3))) void*)ldst, 16, 0, 0);
}

__device__ __forceinline__ void compute_tile(
    size_t rowbase, int r, int c,
    float4 i0, float4 i1, float4 b0, float4 b1,
    const short8v (&hAf)[3][2], const short8v (&gAf)[3][2],
    const short8v (&w2f)[3][2], float* __restrict__ out) {
  const f32x4 z = {0.f, 0.f, 0.f, 0.f};
  short8v xa0, xa1;
  xa0[0] = (short)f2bf(i0.x); xa0[1] = (short)f2bf(i0.y);
  xa0[2] = (short)f2bf(i0.z); xa0[3] = (short)f2bf(i0.w);
  xa0[4] = (short)f2bf(i1.x); xa0[5] = (short)f2bf(i1.y);
  xa0[6] = (short)f2bf(i1.z); xa0[7] = (short)f2bf(i1.w);
  xa1[0] = (short)f2bf(b0.x); xa1[1] = (short)f2bf(b0.y);
  xa1[2] = (short)f2bf(b0.z); xa1[3] = (short)f2bf(b0.w);
  xa1[4] = (short)f2bf(b1.x); xa1[5] = (short)f2bf(b1.y);
  xa1[6] = (short)f2bf(b1.z); xa1[7] = (short)f2bf(b1.w);

  f32x4 hacc[3], gacc[3];
#pragma unroll
  for (int go = 0; go < 3; ++go)
    hacc[go] = __builtin_amdgcn_mfma_f32_16x16x32_bf16(
        hAf[go][1], xa1,
        __builtin_amdgcn_mfma_f32_16x16x32_bf16(hAf[go][0], xa0, z, 0, 0, 0),
        0, 0, 0);
#pragma unroll
  for (int go = 0; go < 3; ++go)
    gacc[go] = __builtin_amdgcn_mfma_f32_16x16x32_bf16(
        gAf[go][1], xa1,
        __builtin_amdgcn_mfma_f32_16x16x32_bf16(gAf[go][0], xa0, z, 0, 0, 0),
        0, 0, 0);

  short8v hb0, hb1;
#pragma unroll
  for (int j = 0; j < 4; ++j) {
    hb0[j]     = (short)f2bf(fmaxf(hacc[0][j], 0.f));
    hb0[j + 4] = (short)f2bf(fmaxf(hacc[1][j], 0.f));
    hb1[j]     = (short)f2bf(fmaxf(hacc[2][j], 0.f));
  }
  hb1[4] = (c == 3) ? (short)0x3F80 : (short)0;  // bias-1.0 in exactly one k-slot
  hb1[5] = 0; hb1[6] = 0; hb1[7] = 0;

  f32x4 oacc[3];
#pragma unroll
  for (int go = 0; go < 3; ++go)
    oacc[go] = __builtin_amdgcn_mfma_f32_16x16x32_bf16(
        w2f[go][1], hb1,
        __builtin_amdgcn_mfma_f32_16x16x32_bf16(w2f[go][0], hb0, z, 0, 0, 0),
        0, 0, 0);

  float* orow = out + (rowbase + r) * 48;
#pragma unroll
  for (int go = 0; go < 3; ++go) {
    float4 v;
    v.x = fmaxf(oacc[go][0], 0.f) * __builtin_amdgcn_rcpf(1.f + __expf(-gacc[go][0]));
    v.y = fmaxf(oacc[go][1], 0.f) * __builtin_amdgcn_rcpf(1.f + __expf(-gacc[go][1]));
    v.z = fmaxf(oacc[go][2], 0.f) * __builtin_amdgcn_rcpf(1.f + __expf(-gacc[go][2]));
    v.w = fmaxf(oacc[go][3], 0.f) * __builtin_amdgcn_rcpf(1.f + __expf(-gacc[go][3]));
    *reinterpret_cast<float4*>(orow + 16 * go + 4 * c) = v;
  }
}

__global__ __launch_bounds__(256) void mfma_main(
    const float* __restrict__ img, const float* __restrict__ txt,
    const unsigned short* __restrict__ wsbf, float* __restrict__ out) {
  __shared__ __align__(16) unsigned short ldsw[18 * 64 * 8];  // 18432 B
  const int tid = threadIdx.x;
  const int wave = tid >> 6;
  const int lane = tid & 63;
  const int r = lane & 15;
  const int c = lane >> 4;

  // ---- stage weight fragments to LDS: 18 linear 1024B chunks (chunk = frag)
  {
    const float* wsrc = reinterpret_cast<const float*>(wsbf);
#pragma unroll
    for (int j = wave; j < 18; j += 4)
      gld_lds16(wsrc + j * 256 + lane * 4,
                reinterpret_cast<float*>(&ldsw[j * 512]));
  }

  const int base = blockIdx.x * 256 + wave * 64;  // 4 tiles of 16 rows

  // ---- issue ALL X loads for all 4 tiles (overlaps weight DMA) ----
  float4 xi0[4], xi1[4], xb0[4], xb1[4];
#pragma unroll
  for (int t = 0; t < 4; ++t) {
    const float* pi = img + (size_t)(base + 16 * t + r) * 40;
    const float* pt = txt + (size_t)(base + 16 * t + r) * 20;
    xi0[t] = *(const float4*)(pi + c * 8);
    xi1[t] = *(const float4*)(pi + c * 8 + 4);
    if (c == 0) {
      xb0[t] = *(const float4*)(pi + 32);
      xb1[t] = *(const float4*)(pi + 36);
    } else if (c == 3) {
      xb0[t] = *(const float4*)(pt + 16);
      xb1[t] = make_float4(1.f, 0.f, 0.f, 0.f);
    } else {
      xb0[t] = *(const float4*)(pt + (c - 1) * 8);
      xb1[t] = *(const float4*)(pt + (c - 1) * 8 + 4);
    }
  }

  asm volatile("s_waitcnt vmcnt(0)" ::: "memory");
  __syncthreads();

  // ---- weight fragments from LDS: canonical conflict-free ds_read_b128 ----
  const short8v* lw = reinterpret_cast<const short8v*>(ldsw);  // [f18][lane]
  short8v hAf[3][2], gAf[3][2], w2f[3][2];
#pragma unroll
  for (int go = 0; go < 3; ++go) {
    hAf[go][0] = lw[(go * 2 + 0) * 64 + lane];
    hAf[go][1] = lw[(go * 2 + 1) * 64 + lane];
    gAf[go][0] = lw[(6 + go * 2 + 0) * 64 + lane];
    gAf[go][1] = lw[(6 + go * 2 + 1) * 64 + lane];
    w2f[go][0] = lw[(12 + go * 2 + 0) * 64 + lane];
    w2f[go][1] = lw[(12 + go * 2 + 1) * 64 + lane];
  }

#pragma unroll
  for (int t = 0; t < 4; ++t)
    compute_tile((size_t)base + 16 * t, r, c, xi0[t], xi1[t], xb0[t], xb1[t],
                 hAf, gAf, w2f, out);
}

extern "C" void kernel_launch(void* const* d_in, const int* in_sizes, int n_in,
                              void* d_out, int out_size, void* d_ws, size_t ws_size,
                              hipStream_t stream) {
  const float* img  = (const float*)d_in[0];
  const float* txt  = (const float*)d_in[1];
  const float* Wiv  = (const float*)d_in[6];
  const float* biv  = (const float*)d_in[7];
  const float* Wtv  = (const float*)d_in[12];
  const float* btv  = (const float*)d_in[13];
  const float* Wisv = (const float*)d_in[18];
  const float* bisv = (const float*)d_in[19];
  const float* Wtsv = (const float*)d_in[24];
  const float* btsv = (const float*)d_in[25];
  const float* Wm1  = (const float*)d_in[26];
  const float* bm1  = (const float*)d_in[27];
  const float* Wm2  = (const float*)d_in[28];
  const float* bm2  = (const float*)d_in[29];
  const float* Wg   = (const float*)d_in[30];
  const float* bg   = (const float*)d_in[31];
  float* out = (float*)d_out;
  unsigned short* wsbf = (unsigned short*)d_ws;  // 18*64*8 bf16 = 18432 B

  const int nrows = in_sizes[0] / 40;  // 262144

  hipLaunchKernelGGL(fold_packed, dim3(36), dim3(256), 0, stream,
                     Wiv, biv, Wtv, btv, Wisv, bisv, Wtsv, btsv,
                     Wm1, bm1, Wm2, bm2, Wg, bg, wsbf);

  const int grid = nrows / 256;  // 1024 blocks x 4 waves x 64 rows
  hipLaunchKernelGGL(mfma_main, dim3(grid), dim3(256), 0, stream,
                     img, txt, wsbf, out);
}

// Round 10
// 29.762 us; speedup vs baseline: 1.2947x; 1.0837x over previous
//
#include <hip/hip_runtime.h>
#include <hip/hip_bf16.h>
#include <math.h>

typedef __attribute__((ext_vector_type(8))) short short8v;  // 8 bf16 in 4 VGPRs
typedef __attribute__((ext_vector_type(4))) float f32x4;

__device__ inline unsigned short f2bf(float f) {
  return __builtin_bit_cast(unsigned short, __float2bfloat16(f));
}

// ---------------------------------------------------------------------------
// fold_packed (unchanged from round 9): pre-packed bf16 weight fragments,
// FRAG-MAJOR layout wsbf[f18][lane][elem] so each 1024B chunk = one fragment
// across 64 lanes (linear for global_load_lds; conflict-free ds_read_b128).
//   frags 0..5  : hAf[go][f] = hA[(16go+r)][32f + 8c + e]   (lane = 16c + r)
//   frags 6..11 : gAf[go][f]   same from gA
//   frags 12..17: w2f[go][f]   delta-permuted W2 (+ b2 at f=1,e=4)
// hA/gA col j: 0..39 img coeff, 40..59 txt coeff, 60 bias, 61..63 zero.
// ---------------------------------------------------------------------------
__global__ __launch_bounds__(256) void fold_packed(
    const float* __restrict__ Wiv, const float* __restrict__ biv,
    const float* __restrict__ Wtv, const float* __restrict__ btv,
    const float* __restrict__ Wisv, const float* __restrict__ bisv,
    const float* __restrict__ Wtsv, const float* __restrict__ btsv,
    const float* __restrict__ Wm1, const float* __restrict__ bm1,
    const float* __restrict__ Wm2, const float* __restrict__ bm2,
    const float* __restrict__ Wg, const float* __restrict__ bg,
    unsigned short* __restrict__ wsbf) {
  const int idx = blockIdx.x * 256 + threadIdx.x;
  if (idx >= 18 * 64 * 8) return;
  const int f18 = idx >> 9;
  const int lane = (idx >> 3) & 63;
  const int e = idx & 7;
  const int r = lane & 15, c = lane >> 4;

  float v = 0.f;
  if (f18 < 12) {
    const bool isH = (f18 < 6);
    const int q = isH ? f18 : f18 - 6;
    const int go = q >> 1, f = q & 1;
    const int row = go * 16 + r;
    const int j = f * 32 + c * 8 + e;
    if (isH) {
      if (j < 40) {
        for (int k = 0; k < 48; ++k) v += Wm1[row * 144 + 48 + k] * Wtv[k * 40 + j];
        for (int k = 0; k < 24; ++k) v += Wm1[row * 144 + 96 + k] * Wisv[k * 40 + j];
      } else if (j < 60) {
        const int jj = j - 40;
        for (int k = 0; k < 48; ++k) v += Wm1[row * 144 + k] * Wiv[k * 20 + jj];
        for (int k = 0; k < 24; ++k) v += Wm1[row * 144 + 120 + k] * Wtsv[k * 20 + jj];
      } else if (j == 60) {
        v = bm1[row];
        for (int k = 0; k < 48; ++k) v += Wm1[row * 144 + k] * biv[k];
        for (int k = 0; k < 48; ++k) v += Wm1[row * 144 + 48 + k] * btv[k];
        for (int k = 0; k < 24; ++k) v += Wm1[row * 144 + 96 + k] * bisv[k];
        for (int k = 0; k < 24; ++k) v += Wm1[row * 144 + 120 + k] * btsv[k];
      }
    } else {
      if (j < 40) {
        for (int k = 0; k < 48; ++k) v += Wg[row * 96 + 48 + k] * Wtv[k * 40 + j];
      } else if (j < 60) {
        const int jj = j - 40;
        for (int k = 0; k < 48; ++k) v += Wg[row * 96 + k] * Wiv[k * 20 + jj];
      } else if (j == 60) {
        v = bg[row];
        for (int k = 0; k < 48; ++k) v += Wg[row * 96 + k] * biv[k];
        for (int k = 0; k < 48; ++k) v += Wg[row * 96 + 48 + k] * btv[k];
      }
    }
  } else {
    const int q = f18 - 12;
    const int f = q & 1;
    const int row = (q >> 1) * 16 + r;
    if (f == 0) {
      const int col = (e < 4) ? (4 * c + e) : (16 + 4 * c + (e - 4));
      v = Wm2[row * 48 + col];
    } else {
      if (e < 4) v = Wm2[row * 48 + 32 + 4 * c + e];
      else if (e == 4) v = bm2[row];
    }
  }
  wsbf[idx] = f2bf(v);
}

// ---------------------------------------------------------------------------
// mfma_main: round-9 weight-LDS staging + round-8 X-LDS staging combined.
// 128 rows/block, 4 waves x 32 rows (2 tiles). 48 fire-and-forget 1024B DMA
// chunks per block (img 20 + txt 10 + weights 18) issued back-to-back ->
// ~48 KB in flight per block, 3 blocks/CU resident (49 KB LDS). One
// vmcnt(0)+barrier; all subsequent reads from LDS.
// ---------------------------------------------------------------------------
__device__ __forceinline__ void gld_lds16(const float* gsrc, float* ldst) {
  __builtin_amdgcn_global_load_lds(
      (const __attribute__((address_space(1))) void*)gsrc,
      (__attribute__((address_space(3))) void*)ldst, 16, 0, 0);
}

__device__ __forceinline__ void compute_tile(
    size_t rowbase, int r, int c,
    float4 i0, float4 i1, float4 b0, float4 b1,
    const short8v (&hAf)[3][2], const short8v (&gAf)[3][2],
    const short8v (&w2f)[3][2], float* __restrict__ out) {
  const f32x4 z = {0.f, 0.f, 0.f, 0.f};
  short8v xa0, xa1;
  xa0[0] = (short)f2bf(i0.x); xa0[1] = (short)f2bf(i0.y);
  xa0[2] = (short)f2bf(i0.z); xa0[3] = (short)f2bf(i0.w);
  xa0[4] = (short)f2bf(i1.x); xa0[5] = (short)f2bf(i1.y);
  xa0[6] = (short)f2bf(i1.z); xa0[7] = (short)f2bf(i1.w);
  xa1[0] = (short)f2bf(b0.x); xa1[1] = (short)f2bf(b0.y);
  xa1[2] = (short)f2bf(b0.z); xa1[3] = (short)f2bf(b0.w);
  xa1[4] = (short)f2bf(b1.x); xa1[5] = (short)f2bf(b1.y);
  xa1[6] = (short)f2bf(b1.z); xa1[7] = (short)f2bf(b1.w);

  f32x4 hacc[3], gacc[3];
#pragma unroll
  for (int go = 0; go < 3; ++go)
    hacc[go] = __builtin_amdgcn_mfma_f32_16x16x32_bf16(
        hAf[go][1], xa1,
        __builtin_amdgcn_mfma_f32_16x16x32_bf16(hAf[go][0], xa0, z, 0, 0, 0),
        0, 0, 0);
#pragma unroll
  for (int go = 0; go < 3; ++go)
    gacc[go] = __builtin_amdgcn_mfma_f32_16x16x32_bf16(
        gAf[go][1], xa1,
        __builtin_amdgcn_mfma_f32_16x16x32_bf16(gAf[go][0], xa0, z, 0, 0, 0),
        0, 0, 0);

  short8v hb0, hb1;
#pragma unroll
  for (int j = 0; j < 4; ++j) {
    hb0[j]     = (short)f2bf(fmaxf(hacc[0][j], 0.f));
    hb0[j + 4] = (short)f2bf(fmaxf(hacc[1][j], 0.f));
    hb1[j]     = (short)f2bf(fmaxf(hacc[2][j], 0.f));
  }
  hb1[4] = (c == 3) ? (short)0x3F80 : (short)0;  // bias-1.0 in exactly one k-slot
  hb1[5] = 0; hb1[6] = 0; hb1[7] = 0;

  f32x4 oacc[3];
#pragma unroll
  for (int go = 0; go < 3; ++go)
    oacc[go] = __builtin_amdgcn_mfma_f32_16x16x32_bf16(
        w2f[go][1], hb1,
        __builtin_amdgcn_mfma_f32_16x16x32_bf16(w2f[go][0], hb0, z, 0, 0, 0),
        0, 0, 0);

  float* orow = out + (rowbase + r) * 48;
#pragma unroll
  for (int go = 0; go < 3; ++go) {
    float4 v;
    v.x = fmaxf(oacc[go][0], 0.f) * __builtin_amdgcn_rcpf(1.f + __expf(-gacc[go][0]));
    v.y = fmaxf(oacc[go][1], 0.f) * __builtin_amdgcn_rcpf(1.f + __expf(-gacc[go][1]));
    v.z = fmaxf(oacc[go][2], 0.f) * __builtin_amdgcn_rcpf(1.f + __expf(-gacc[go][2]));
    v.w = fmaxf(oacc[go][3], 0.f) * __builtin_amdgcn_rcpf(1.f + __expf(-gacc[go][3]));
    *reinterpret_cast<float4*>(orow + 16 * go + 4 * c) = v;
  }
}

__global__ __launch_bounds__(256) void mfma_main(
    const float* __restrict__ img, const float* __restrict__ txt,
    const unsigned short* __restrict__ wsbf, float* __restrict__ out) {
  __shared__ __align__(16) float simg[128 * 40];            // 20480 B
  __shared__ __align__(16) float stxt[128 * 20];            // 10240 B
  __shared__ __align__(16) unsigned short ldsw[18 * 512];   // 18432 B
  const int tid = threadIdx.x;
  const int wave = tid >> 6;
  const int lane = tid & 63;
  const int r = lane & 15;
  const int c = lane >> 4;
  const size_t row0 = (size_t)blockIdx.x * 128;

  // ---- issue ALL staging DMA back-to-back: 48 KB in flight per block ----
  {
    const float* wsrc = reinterpret_cast<const float*>(wsbf);
#pragma unroll
    for (int j = wave; j < 18; j += 4)
      gld_lds16(wsrc + j * 256 + lane * 4,
                reinterpret_cast<float*>(&ldsw[j * 512]));
    const float* gi = img + row0 * 40;
#pragma unroll
    for (int j = wave; j < 20; j += 4)
      gld_lds16(gi + j * 256 + lane * 4, &simg[j * 256]);
    const float* gt = txt + row0 * 20;
#pragma unroll
    for (int j = wave; j < 10; j += 4)
      gld_lds16(gt + j * 256 + lane * 4, &stxt[j * 256]);
  }

  asm volatile("s_waitcnt vmcnt(0)" ::: "memory");
  __syncthreads();

  // ---- weight fragments from LDS: conflict-free ds_read_b128 ----
  const short8v* lw = reinterpret_cast<const short8v*>(ldsw);  // [f18][lane]
  short8v hAf[3][2], gAf[3][2], w2f[3][2];
#pragma unroll
  for (int go = 0; go < 3; ++go) {
    hAf[go][0] = lw[(go * 2 + 0) * 64 + lane];
    hAf[go][1] = lw[(go * 2 + 1) * 64 + lane];
    gAf[go][0] = lw[(6 + go * 2 + 0) * 64 + lane];
    gAf[go][1] = lw[(6 + go * 2 + 1) * 64 + lane];
    w2f[go][0] = lw[(12 + go * 2 + 0) * 64 + lane];
    w2f[go][1] = lw[(12 + go * 2 + 1) * 64 + lane];
  }

  // ---- 2 tiles of 16 rows per wave, X fragments via ds_read_b128 ----
#pragma unroll
  for (int t = 0; t < 2; ++t) {
    const int lrow = wave * 32 + t * 16 + r;  // block-local row
    float4 xi0 = *(const float4*)&simg[lrow * 40 + c * 8];
    float4 xi1 = *(const float4*)&simg[lrow * 40 + c * 8 + 4];
    float4 xb0, xb1;
    if (c == 0) {
      xb0 = *(const float4*)&simg[lrow * 40 + 32];
      xb1 = *(const float4*)&simg[lrow * 40 + 36];
    } else if (c == 3) {
      xb0 = *(const float4*)&stxt[lrow * 20 + 16];
      xb1 = make_float4(1.f, 0.f, 0.f, 0.f);
    } else {
      xb0 = *(const float4*)&stxt[lrow * 20 + (c - 1) * 8];
      xb1 = *(const float4*)&stxt[lrow * 20 + (c - 1) * 8 + 4];
    }
    compute_tile(row0 + wave * 32 + t * 16, r, c, xi0, xi1, xb0, xb1,
                 hAf, gAf, w2f, out);
  }
}

extern "C" void kernel_launch(void* const* d_in, const int* in_sizes, int n_in,
                              void* d_out, int out_size, void* d_ws, size_t ws_size,
                              hipStream_t stream) {
  const float* img  = (const float*)d_in[0];
  const float* txt  = (const float*)d_in[1];
  const float* Wiv  = (const float*)d_in[6];
  const float* biv  = (const float*)d_in[7];
  const float* Wtv  = (const float*)d_in[12];
  const float* btv  = (const float*)d_in[13];
  const float* Wisv = (const float*)d_in[18];
  const float* bisv = (const float*)d_in[19];
  const float* Wtsv = (const float*)d_in[24];
  const float* btsv = (const float*)d_in[25];
  const float* Wm1  = (const float*)d_in[26];
  const float* bm1  = (const float*)d_in[27];
  const float* Wm2  = (const float*)d_in[28];
  const float* bm2  = (const float*)d_in[29];
  const float* Wg   = (const float*)d_in[30];
  const float* bg   = (const float*)d_in[31];
  float* out = (float*)d_out;
  unsigned short* wsbf = (unsigned short*)d_ws;  // 18*64*8 bf16 = 18432 B

  const int nrows = in_sizes[0] / 40;  // 262144

  hipLaunchKernelGGL(fold_packed, dim3(36), dim3(256), 0, stream,
                     Wiv, biv, Wtv, btv, Wisv, bisv, Wtsv, btsv,
                     Wm1, bm1, Wm2, bm2, Wg, bg, wsbf);

  const int grid = nrows / 128;  // 2048 blocks x 4 waves x 32 rows
  hipLaunchKernelGGL(mfma_main, dim3(grid), dim3(256), 0, stream,
                     img, txt, wsbf, out);
}